// Round 1
// baseline (149.625 us; speedup 1.0000x reference)
//
#include <hip/hip_runtime.h>

#define TPB 256
#define NBLOCKS 2048

__device__ __forceinline__ float fade_f(float t) {
    // 6t^5 - 15t^4 + 10t^3
    return t * t * t * (t * (t * 6.0f - 15.0f) + 10.0f);
}

__device__ __forceinline__ float lerp_f(float a, float b, float t) {
    return fmaf(t, b - a, a);
}

// grad3 rows: 0..3 = (±1,±1,0), 4..7 = (±1,0,±1), 8..11 = (0,±1,±1)
// group = gi>>2 selects component pair; gi&1 / gi&2 are the two sign bits.
__device__ __forceinline__ float gdot(unsigned gi, float dx, float dy, float dz) {
    unsigned g = gi >> 2;
    float c1 = (g < 2u) ? dx : dy;   // groups 0,1 use x first; group 2 uses y
    float c2 = (g == 0u) ? dy : dz;  // group 0 uses y second; groups 1,2 use z
    unsigned u1 = __float_as_uint(c1) ^ ((gi & 1u) << 31);
    unsigned u2 = __float_as_uint(c2) ^ ((gi & 2u) << 30);
    return __uint_as_float(u1) + __uint_as_float(u2);
}

__global__ __launch_bounds__(TPB, 4) void perlin_kernel(
    const float* __restrict__ xg, const float* __restrict__ yg,
    const float* __restrict__ zg, const int* __restrict__ perm,
    float* __restrict__ out, int nquads)
{
    // 32-way replicated packed perm table: entry i of copy c at word i*32+c
    // -> copy c occupies bank c only. Lane reads its own copy (lane&31):
    // lanes i and i+32 share a bank = 2-way = free.
    // Packed word: perm[i] in bits 0..7, perm[i]%12 in bits 8..11.
    __shared__ unsigned T[256 * 32];  // 32 KB

    for (int s = threadIdx.x; s < 256 * 32; s += TPB) {
        unsigned pv = (unsigned)perm[s >> 5];
        T[s] = pv | ((pv % 12u) << 8);  // (w + k) & 255 == (perm[i] + k) & 255
    }
    __syncthreads();

    const unsigned* Tl = T + (threadIdx.x & 31);

    const float4* x4 = (const float4*)xg;
    const float4* y4 = (const float4*)yg;
    const float4* z4 = (const float4*)zg;
    float4* o4 = (float4*)out;

    const int stride = gridDim.x * TPB;
    for (int q = blockIdx.x * TPB + threadIdx.x; q < nquads; q += stride) {
        float4 xv = x4[q], yv = y4[q], zv = z4[q];
        float xa[4] = {xv.x, xv.y, xv.z, xv.w};
        float ya[4] = {yv.x, yv.y, yv.z, yv.w};
        float za[4] = {zv.x, zv.y, zv.z, zv.w};
        float res[4];

        #pragma unroll
        for (int e = 0; e < 4; ++e) {
            float X = xa[e], Y = ya[e], Z = za[e];
            float fx = floorf(X), fy = floorf(Y), fz = floorf(Z);
            float xf = X - fx, yf = Y - fy, zf = Z - fz;
            int xi = ((int)fx) & 255;
            int yi = ((int)fy) & 255;
            int zi = ((int)fz) & 255;
            float u = fade_f(xf), v = fade_f(yf), w = fade_f(zf);
            float xf1 = xf - 1.0f, yf1 = yf - 1.0f, zf1 = zf - 1.0f;

            // hash tree: 2 + 4 + 8 lookups (packed high bits die under &255)
            #define LK(i) Tl[((unsigned)(i) & 255u) << 5]
            unsigned A  = LK(xi),         B  = LK(xi + 1);
            unsigned aa = LK(A + yi),     ab = LK(A + yi + 1);
            unsigned ba = LK(B + yi),     bb = LK(B + yi + 1);
            unsigned haaa = LK(aa + zi) >> 8, haab = LK(aa + zi + 1) >> 8;
            unsigned haba = LK(ab + zi) >> 8, habb = LK(ab + zi + 1) >> 8;
            unsigned hbaa = LK(ba + zi) >> 8, hbab = LK(ba + zi + 1) >> 8;
            unsigned hbba = LK(bb + zi) >> 8, hbbb = LK(bb + zi + 1) >> 8;
            #undef LK

            float g_aaa = gdot(haaa, xf,  yf,  zf);
            float g_aab = gdot(haab, xf,  yf,  zf1);
            float g_aba = gdot(haba, xf,  yf1, zf);
            float g_abb = gdot(habb, xf,  yf1, zf1);
            float g_baa = gdot(hbaa, xf1, yf,  zf);
            float g_bab = gdot(hbab, xf1, yf,  zf1);
            float g_bba = gdot(hbba, xf1, yf1, zf);
            float g_bbb = gdot(hbbb, xf1, yf1, zf1);

            float l1 = lerp_f(g_aaa, g_baa, u);
            float l2 = lerp_f(g_aba, g_bba, u);
            float l3 = lerp_f(g_aab, g_bab, u);
            float l4 = lerp_f(g_abb, g_bbb, u);
            float m1 = lerp_f(l1, l2, v);
            float m2 = lerp_f(l3, l4, v);
            res[e] = lerp_f(m1, m2, w);
        }
        o4[q] = make_float4(res[0], res[1], res[2], res[3]);
    }
}

extern "C" void kernel_launch(void* const* d_in, const int* in_sizes, int n_in,
                              void* d_out, int out_size, void* d_ws, size_t ws_size,
                              hipStream_t stream) {
    const float* x   = (const float*)d_in[0];
    const float* y   = (const float*)d_in[1];
    const float* z   = (const float*)d_in[2];
    const int* perm  = (const int*)d_in[3];
    // d_in[4] (grad3) unused: gradients computed arithmetically from the index
    float* out = (float*)d_out;
    int nquads = out_size >> 2;  // GRID = 32*512*512, divisible by 4
    perlin_kernel<<<NBLOCKS, TPB, 0, stream>>>(x, y, z, perm, out, nquads);
}

// Round 2
// 141.599 us; speedup vs baseline: 1.0567x; 1.0567x over previous
//
#include <hip/hip_runtime.h>

#define TPB 256
#define NBLOCKS 2048   // 8 blocks/CU x 256 CU: exactly fills 32 waves/CU
#define REPL 16        // 16-way table replication -> 16 KB LDS

__device__ __forceinline__ float fade_f(float t) {
    // 6t^5 - 15t^4 + 10t^3 (Horner, fmaf)
    return t * t * t * fmaf(t, fmaf(t, 6.0f, -15.0f), 10.0f);
}

__device__ __forceinline__ float lerp_f(float a, float b, float t) {
    return fmaf(t, b - a, a);
}

// Leaf word w carries gi = perm[...] % 12 in bits 0..5.
// grad3 rows: 0..3 = (±1,±1,0), 4..7 = (±1,0,±1), 8..11 = (0,±1,±1)
// c1 = gi<8 ? dx : dy ; c2 = gi<4 ? dy : dz ; signs = gi&1, gi&2.
__device__ __forceinline__ float gdot_w(unsigned w, float dx, float dy, float dz) {
    unsigned gi = w & 0x3Fu;
    float c1 = (gi < 8u) ? dx : dy;
    float c2 = (gi < 4u) ? dy : dz;
    unsigned s1 = w << 31;                    // bit0 -> sign
    unsigned s2 = (w << 30) & 0x80000000u;    // bit1 -> sign
    return __uint_as_float(__float_as_uint(c1) ^ s1)
         + __uint_as_float(__float_as_uint(c2) ^ s2);
}

__global__ __launch_bounds__(TPB, 8) void perlin_kernel(
    const float* __restrict__ xg, const float* __restrict__ yg,
    const float* __restrict__ zg, const int* __restrict__ perm,
    float* __restrict__ out, int nquads)
{
    // 16-way replicated table. Entry i of copy c at word i*16+c.
    // Word = (perm[i] << 6) | (perm[i] % 12).
    //   - bits 6..13 hold perm value pre-scaled to the 64-byte entry stride,
    //     so (w + k<<6) & 0x3FC0 IS the next entry's byte offset (no shift).
    //   - low 6 bits (gi) and any carry above bit 13 die under the mask.
    __shared__ unsigned T[256 * REPL];  // 16 KB

    for (int s = threadIdx.x; s < 256 * REPL; s += TPB) {
        unsigned pv = (unsigned)perm[s >> 4];
        T[s] = (pv << 6) | (pv % 12u);
    }
    __syncthreads();

    const char* Tl = (const char*)T + ((threadIdx.x & (REPL - 1)) << 2);

    const float4* x4 = (const float4*)xg;
    const float4* y4 = (const float4*)yg;
    const float4* z4 = (const float4*)zg;
    float4* o4 = (float4*)out;

    const int stride = gridDim.x * TPB;
    for (int q = blockIdx.x * TPB + threadIdx.x; q < nquads; q += stride) {
        float4 xv = x4[q], yv = y4[q], zv = z4[q];
        float xa[4] = {xv.x, xv.y, xv.z, xv.w};
        float ya[4] = {yv.x, yv.y, yv.z, yv.w};
        float za[4] = {zv.x, zv.y, zv.z, zv.w};
        float4 res;
        float* rp = &res.x;

        #pragma unroll
        for (int e = 0; e < 4; ++e) {
            float X = xa[e], Y = ya[e], Z = za[e];
            float fx = floorf(X), fy = floorf(Y), fz = floorf(Z);
            float xf = X - fx, yf = Y - fy, zf = Z - fz;
            // byte-offset lattice coords (entry stride = 64 B)
            unsigned x6 = ((unsigned)(int)fx << 6) & 0x3FC0u;
            unsigned y6 = ((unsigned)(int)fy << 6);
            unsigned z6 = ((unsigned)(int)fz << 6);
            float u = fade_f(xf), v = fade_f(yf), w = fade_f(zf);
            float xf1 = xf - 1.0f, yf1 = yf - 1.0f, zf1 = zf - 1.0f;

            // hash tree: 2 + 4 + 8 LDS lookups, addresses in byte space
            #define LK(off) (*(const unsigned*)(Tl + ((off) & 0x3FC0u)))
            unsigned A  = LK(x6),          B  = LK(x6 + 64);
            unsigned aa = LK(A + y6),      ab = LK(A + y6 + 64);
            unsigned ba = LK(B + y6),      bb = LK(B + y6 + 64);
            unsigned waaa = LK(aa + z6),   waab = LK(aa + z6 + 64);
            unsigned waba = LK(ab + z6),   wabb = LK(ab + z6 + 64);
            unsigned wbaa = LK(ba + z6),   wbab = LK(ba + z6 + 64);
            unsigned wbba = LK(bb + z6),   wbbb = LK(bb + z6 + 64);
            #undef LK

            float g_aaa = gdot_w(waaa, xf,  yf,  zf);
            float g_aab = gdot_w(waab, xf,  yf,  zf1);
            float g_aba = gdot_w(waba, xf,  yf1, zf);
            float g_abb = gdot_w(wabb, xf,  yf1, zf1);
            float g_baa = gdot_w(wbaa, xf1, yf,  zf);
            float g_bab = gdot_w(wbab, xf1, yf,  zf1);
            float g_bba = gdot_w(wbba, xf1, yf1, zf);
            float g_bbb = gdot_w(wbbb, xf1, yf1, zf1);

            float l1 = lerp_f(g_aaa, g_baa, u);
            float l2 = lerp_f(g_aba, g_bba, u);
            float l3 = lerp_f(g_aab, g_bab, u);
            float l4 = lerp_f(g_abb, g_bbb, u);
            float m1 = lerp_f(l1, l2, v);
            float m2 = lerp_f(l3, l4, v);
            rp[e] = lerp_f(m1, m2, w);
        }
        o4[q] = res;
    }
}

extern "C" void kernel_launch(void* const* d_in, const int* in_sizes, int n_in,
                              void* d_out, int out_size, void* d_ws, size_t ws_size,
                              hipStream_t stream) {
    const float* x   = (const float*)d_in[0];
    const float* y   = (const float*)d_in[1];
    const float* z   = (const float*)d_in[2];
    const int* perm  = (const int*)d_in[3];
    // d_in[4] (grad3) unused: gradients derived arithmetically from the index
    float* out = (float*)d_out;
    int nquads = out_size >> 2;  // 32*512*512 divisible by 4
    perlin_kernel<<<NBLOCKS, TPB, 0, stream>>>(x, y, z, perm, out, nquads);
}